// Round 5
// baseline (367.843 us; speedup 1.0000x reference)
//
#include <hip/hip_runtime.h>

// NoMCOutModel round 19: r18 + balanced produce (18 tiles/wave) + it-top
// register prefetch of all ws tiles.
// r18 post-mortem: scan fix gained 13us (202->189) -> scan now ~20us;
// produce+m_in ~155us dominates. Produce defects: (1) 4/5-group imbalance
// (72 groups / 16 waves): barrier waits on the 5-group waves, ~11% of
// produce; (2) runtime ngrp blocks unrolling, so each group's 4 L2 tile
// loads stall the group head; (3) gg<64 branch in the hot loop.
// This round: wave w owns R groups {4w..4w+3}; wave pair (2a,2a+1) splits
// J group 64+a (2 tiles each; halves merged via ph[16][16] + one extra
// barrier). Every wave = 18 tiles exactly; both loops compile-time ->
// full unroll; all 18 tile loads + biases issued at it-top into regs
// (~110 VGPR peak, <=128 cap). Scan/m_in/prep/epilogue: identical to r18.

namespace {

constexpr int B_ = 256, T_ = 256, M_ = 8, AUX_ = 32, H_ = 64;
constexpr int NTILE = 288;               // (64*64 + 8*64)/16 logit col-tiles
constexpr float LOG2E = 1.4426950408889634f;

typedef __fp16 f16x2 __attribute__((ext_vector_type(2)));
typedef __fp16 f16x8 __attribute__((ext_vector_type(8)));
typedef float  f32x4 __attribute__((ext_vector_type(4)));
typedef int    i32x4 __attribute__((ext_vector_type(4)));

union V8 { f16x8 v; f16x2 p[4]; i32x4 i; };

#if __has_builtin(__builtin_amdgcn_exp2f)
#define EXP2(x) __builtin_amdgcn_exp2f(x)
#else
#define EXP2(x) exp2f(x)
#endif

#define MFMA16(A, Bv, C) __builtin_amdgcn_mfma_f32_16x16x32_f16((A), (Bv), (C), 0, 0, 0)

__device__ __forceinline__ float dot2(f16x2 a, f16x2 b, float c) {
    return __builtin_amdgcn_fdot2(a, b, c, false);
}

template <int CTRL>
__device__ __forceinline__ float dpp_add(float v) {
    int t = __builtin_amdgcn_update_dpp(0, __builtin_bit_cast(int, v),
                                        CTRL, 0xf, 0xf, true);
    return v + __builtin_bit_cast(float, t);
}
__device__ __forceinline__ float sum16_all(float v) {
    v = dpp_add<0xB1>(v);   // quad_perm [1,0,3,2]
    v = dpp_add<0x4E>(v);   // quad_perm [2,3,0,1]
    v = dpp_add<0x141>(v);  // row_half_mirror
    v = dpp_add<0x140>(v);  // row_mirror
    return v;
}
__device__ __forceinline__ float sum64_uni(float v) {
    v = dpp_add<0x111>(v); v = dpp_add<0x112>(v); v = dpp_add<0x114>(v);
    v = dpp_add<0x118>(v); v = dpp_add<0x142>(v); v = dpp_add<0x143>(v);
    return __builtin_bit_cast(float,
        __builtin_amdgcn_readlane(__builtin_bit_cast(int, v), 63));
}

// RNE pair-pack: every lane ends with (f16(chat[2P]), f16(chat[2P+1])) where
// P = lane>>1. Own value is converted RNE ((__fp16) cast = v_cvt_f16_f32),
// then quad_perm DPP broadcasts the even/odd pair members to both lanes.
__device__ __forceinline__ int pack_pair_rne(float v) {
    const int hv = (int)__builtin_bit_cast(unsigned short, (__fp16)v);
    const int ev = __builtin_amdgcn_update_dpp(0, hv, 0xA0, 0xf, 0xf, true); // [0,0,2,2]
    const int ov = __builtin_amdgcn_update_dpp(0, hv, 0xF5, 0xf, 0xf, true); // [1,1,3,3]
    return ev | (ov << 16);
}

#define LDS_FENCE() __asm__ volatile("s_waitcnt lgkmcnt(0)" ::: "memory")

// ---------------- prep: W -> f16 MFMA B-frag layout in ws ----------------
// ws[gt*1024 + lane*16] : f16x8 frag, B[k = (lane>>4)*8 + j][n = gt*16+(lane&15)]
// ws + 288*1024 : float bias[4608] (log2e-scaled)
__global__ __launch_bounds__(64)
void nomc_prep(const float* __restrict__ Wj, const float* __restrict__ bj,
               const float* __restrict__ Wr, const float* __restrict__ br,
               void* __restrict__ ws)
{
    const int gt = blockIdx.x;           // 0..287
    const int l = threadIdx.x, q = l >> 4, l15 = l & 15;
    const float* src; const float* bsrc; int stride;
    if (gt < 256) { const int n = gt * 16 + l15;        src = Wr + n; bsrc = br + n; stride = 4096; }
    else          { const int n = (gt - 256) * 16 + l15; src = Wj + n; bsrc = bj + n; stride = 512; }
    V8 v;
#pragma unroll
    for (int j = 0; j < 4; ++j) {
        const float f0 = src[(q * 8 + 2 * j)     * stride] * LOG2E;
        const float f1 = src[(q * 8 + 2 * j + 1) * stride] * LOG2E;
        v.p[j] = __builtin_amdgcn_cvt_pkrtz(f0, f1);
    }
    *(i32x4*)((char*)ws + (size_t)gt * 1024 + l * 16) = v.i;
    if (l < 16)
        ((float*)((char*)ws + NTILE * 1024))[gt * 16 + l] = bsrc[0] * LOG2E;
}

// ---------------- main ----------------
__global__ __launch_bounds__(1024, 4)
void nomc_main(const float* __restrict__ x_m, const float* __restrict__ x_a,
               const float* __restrict__ Wo, const float* __restrict__ bo,
               const float* __restrict__ Wfc, const float* __restrict__ bfc,
               const void* __restrict__ ws, float* __restrict__ out)
{
    const int b = blockIdx.x, tid = threadIdx.x;
    const int w = tid >> 6, l = tid & 63, q = l >> 4, l15 = l & 15;

    __shared__ __align__(16) __fp16 RT[16][8][64][8];   // 131072 B  RT[t][h>>3][k][(h&7)^((t>>2)<<1)]=e
    __shared__ __align__(16) __fp16 JT[16][64][8];      //  16384 B  JT[t][k][m^((t>>2)<<1)]=e_j
    __shared__ float sinv[16][64];                      //   4096 B  1/rowsum(R)
    __shared__ __align__(16) __fp16 xj[16][8];          //    256 B  [t][m^((t>>2)<<1)]=xm/s_j
    __shared__ __align__(16) __fp16 minL[16][64];       //   2048 B  m_in[t][k]
    __shared__ float xm_lds[T_][M_];                    //   8192 B
    __shared__ float cfin_lds[H_];                      //    256 B
    __shared__ float ph[16][16];                        //   1024 B  J half-rowsums [wave][t]
    // total 163328 <= 163840

    {   // stage x_m once
        const float* xmb = x_m + (size_t)b * T_ * M_;
        for (int i = tid; i < T_ * M_; i += 1024) (&xm_lds[0][0])[i] = xmb[i];
    }
    __syncthreads();

    // Balanced produce: wave w owns R groups {4w..4w+3} (16 tiles) + half of
    // J group 64+(w>>1): tiles tt in {0,1} for even w, {2,3} for odd w.
    const char* wsb = (const char*)ws;
    const float* wbias = (const float*)(wsb + NTILE * 1024);
    const int a_sh = w >> 1;                 // shared J group -> m = a_sh
    const int tb = (w & 1) ? 2 : 0;          // J tile base

    const int sx = q << 1;               // store-side bank swizzle (= (t>>2)<<1)

    float c0 = 0.f, c1 = 0.f, c2 = 0.f, c3 = 0.f;   // c[kt*16 + l15], q-replicated

    for (int it = 0; it < 16; ++it) {
        // ================= produce: 16 timesteps of exp(logits) =================
        V8 af;
        {   // A-frag: row = l15 -> t = it*16+l15; k = q*8+j
            const float* xa = x_a + ((size_t)b * T_ + it * 16 + l15) * AUX_ + q * 8;
            const f32x4 x0 = *(const f32x4*)xa;
            const f32x4 x1 = *(const f32x4*)(xa + 4);
            af.p[0] = __builtin_amdgcn_cvt_pkrtz(x0.x, x0.y);
            af.p[1] = __builtin_amdgcn_cvt_pkrtz(x0.z, x0.w);
            af.p[2] = __builtin_amdgcn_cvt_pkrtz(x1.x, x1.y);
            af.p[3] = __builtin_amdgcn_cvt_pkrtz(x1.z, x1.w);
        }

        // ---- it-top prefetch: all 18 tiles + biases into regs ----
        V8 tj[2]; float bvj[2];
#pragma unroll
        for (int s = 0; s < 2; ++s) {
            const int gt = (64 + a_sh) * 4 + tb + s;
            tj[s].i = *(const i32x4*)(wsb + (size_t)gt * 1024 + l * 16);
            bvj[s] = wbias[gt * 16 + l15];
        }
        V8 tr[4][4]; float bvr[4][4];
#pragma unroll
        for (int g = 0; g < 4; ++g) {
#pragma unroll
            for (int tt = 0; tt < 4; ++tt) {
                const int gt = (w * 4 + g) * 4 + tt;
                tr[g][tt].i = *(const i32x4*)(wsb + (size_t)gt * 1024 + l * 16);
                bvr[g][tt] = wbias[gt * 16 + l15];
            }
        }

        // ---- J half: 2 tiles of group 64+a_sh ----
        {
            float ej0 = 0.f, ej1 = 0.f, ej2 = 0.f, ej3 = 0.f;
#pragma unroll
            for (int s = 0; s < 2; ++s) {
                const int tt = tb + s;
                const float bv = bvj[s];
                f32x4 acc = {bv, bv, bv, bv};
                acc = MFMA16(af.v, tj[s].v, acc);
                const float e0 = EXP2(acc[0]), e1 = EXP2(acc[1]);
                const float e2 = EXP2(acc[2]), e3 = EXP2(acc[3]);
                const int kk = (tt << 4) + l15;
                const int mp = a_sh ^ sx;
                JT[q * 4 + 0][kk][mp] = (__fp16)e0;
                JT[q * 4 + 1][kk][mp] = (__fp16)e1;
                JT[q * 4 + 2][kk][mp] = (__fp16)e2;
                JT[q * 4 + 3][kk][mp] = (__fp16)e3;
                ej0 += e0; ej1 += e1; ej2 += e2; ej3 += e3;
            }
            ej0 = sum16_all(ej0); ej1 = sum16_all(ej1);
            ej2 = sum16_all(ej2); ej3 = sum16_all(ej3);
            if (l15 == 0) {
                ph[w][q * 4 + 0] = ej0;
                ph[w][q * 4 + 1] = ej1;
                ph[w][q * 4 + 2] = ej2;
                ph[w][q * 4 + 3] = ej3;
            }
        }
        __syncthreads();   // barrier A: ph visible

        // ---- 4 full R groups ----
#pragma unroll
        for (int g = 0; g < 4; ++g) {
            const int gg = w * 4 + g;                    // 0..63
            float es0 = 0.f, es1 = 0.f, es2 = 0.f, es3 = 0.f;
#pragma unroll
            for (int tt = 0; tt < 4; ++tt) {
                const float bv = bvr[g][tt];
                f32x4 acc = {bv, bv, bv, bv};
                acc = MFMA16(af.v, tr[g][tt].v, acc);
                const float e0 = EXP2(acc[0]), e1 = EXP2(acc[1]);
                const float e2 = EXP2(acc[2]), e3 = EXP2(acc[3]);
                const int kk = (tt << 4) + l15;
                const int hb = gg >> 3, p = (gg & 7) ^ sx;  // swizzled slot
                RT[q * 4 + 0][hb][kk][p] = (__fp16)e0;
                RT[q * 4 + 1][hb][kk][p] = (__fp16)e1;
                RT[q * 4 + 2][hb][kk][p] = (__fp16)e2;
                RT[q * 4 + 3][hb][kk][p] = (__fp16)e3;
                es0 += e0; es1 += e1; es2 += e2; es3 += e3;
            }
            const float sr0 = sum16_all(es0), sr1 = sum16_all(es1);
            const float sr2 = sum16_all(es2), sr3 = sum16_all(es3);
            if (l15 == 0) {
                sinv[q * 4 + 0][gg] = __builtin_amdgcn_rcpf(sr0);
                sinv[q * 4 + 1][gg] = __builtin_amdgcn_rcpf(sr1);
                sinv[q * 4 + 2][gg] = __builtin_amdgcn_rcpf(sr2);
                sinv[q * 4 + 3][gg] = __builtin_amdgcn_rcpf(sr3);
            }
        }

        // ---- J finalize: merge half-rowsums, write xj (even wave only) ----
        if ((w & 1) == 0 && l15 == 0) {
#pragma unroll
            for (int r = 0; r < 4; ++r) {
                const int t = q * 4 + r;
                const float tot = ph[w][t] + ph[w + 1][t];
                xj[t][a_sh ^ sx] =
                    (__fp16)(xm_lds[it * 16 + t][a_sh] * __builtin_amdgcn_rcpf(tot));
            }
        }
        __syncthreads();   // barrier B: produce complete

        // ====== m_in pass (parallel, c-independent): minL[t][k] = xj[t].JT[t][k] ======
        // JT and xj carry the SAME (w>>2)-dependent k-permutation inside each
        // 16B chunk, so the dot2 pairs still line up.
        {
            V8 jv; jv.v = *(const f16x8*)&JT[w][l][0];
            V8 xv; xv.v = *(const f16x8*)&xj[w][0];
            float s = 0.f;
            s = dot2(jv.p[0], xv.p[0], s);
            s = dot2(jv.p[1], xv.p[1], s);
            s = dot2(jv.p[2], xv.p[2], s);
            s = dot2(jv.p[3], xv.p[3], s);
            minL[w][l] = (__fp16)s;
        }
        __syncthreads();   // barrier C

        // ================= scan: 16 serial MFMA matvecs (wave 15) =================
        // cbuf-free: chat pair-packed in-register (RNE), redistributed by
        // bpermute from the SERVING lane (lane 2P holds chat pair P).
        if (w == 15) {
            const int ab = q << 5;              // A0 byte base = lane 8q
            for (int u = 0; u < 16; ++u) {
                const int sig = (u >> 2) & 3;   // matches producer swizzle
                // ---- c-independent prefetch (no fences -> compiler pipelines) ----
                const float mi0 = (float)minL[u][l15];
                const float mi1 = (float)minL[u][16 + l15];
                const float mi2 = (float)minL[u][32 + l15];
                const float mi3 = (float)minL[u][48 + l15];
                const float svl = sinv[u][l];
                V8 b00, b01, b10, b11, b20, b21, b30, b31;
                b00.v = *(const f16x8*)&RT[u][q][l15][0];
                b01.v = *(const f16x8*)&RT[u][4 + q][l15][0];
                b10.v = *(const f16x8*)&RT[u][q][16 + l15][0];
                b11.v = *(const f16x8*)&RT[u][4 + q][16 + l15][0];
                b20.v = *(const f16x8*)&RT[u][q][32 + l15][0];
                b21.v = *(const f16x8*)&RT[u][4 + q][32 + l15][0];
                b30.v = *(const f16x8*)&RT[u][q][48 + l15][0];
                b31.v = *(const f16x8*)&RT[u][4 + q][48 + l15][0];
                // ---- chat_l = c[l] * sinv[u][l]  (the r15 cbuf value, in-reg) ----
                const float cown = (q == 0) ? c0 : (q == 1) ? c1 : (q == 2) ? c2 : c3;
                const int spk = pack_pair_rne(cown * svl);  // lane pair 2P,2P+1 -> chat pair P
                // ---- A-frags via bpermute: A0 pair jp <- lane 8q+2(jp^sig);
                //      A1 pair jp <- lane 32+8q+2(jp^sig) (offset 128 folds) ----
                V8 A0f, A1f;
                A0f.i[0] = __builtin_amdgcn_ds_bpermute(ab + ((0 ^ sig) << 3), spk);
                A0f.i[1] = __builtin_amdgcn_ds_bpermute(ab + ((1 ^ sig) << 3), spk);
                A0f.i[2] = __builtin_amdgcn_ds_bpermute(ab + ((2 ^ sig) << 3), spk);
                A0f.i[3] = __builtin_amdgcn_ds_bpermute(ab + ((3 ^ sig) << 3), spk);
                A1f.i[0] = __builtin_amdgcn_ds_bpermute(128 + ab + ((0 ^ sig) << 3), spk);
                A1f.i[1] = __builtin_amdgcn_ds_bpermute(128 + ab + ((1 ^ sig) << 3), spk);
                A1f.i[2] = __builtin_amdgcn_ds_bpermute(128 + ab + ((2 ^ sig) << 3), spk);
                A1f.i[3] = __builtin_amdgcn_ds_bpermute(128 + ab + ((3 ^ sig) << 3), spk);
                // ---- 2-deep MFMA chains, C-init = m_in ----
                f32x4 a0 = {mi0, mi0, mi0, mi0};
                a0 = MFMA16(A0f.v, b00.v, a0);
                a0 = MFMA16(A1f.v, b01.v, a0);
                f32x4 a1 = {mi1, mi1, mi1, mi1};
                a1 = MFMA16(A0f.v, b10.v, a1);
                a1 = MFMA16(A1f.v, b11.v, a1);
                f32x4 a2 = {mi2, mi2, mi2, mi2};
                a2 = MFMA16(A0f.v, b20.v, a2);
                a2 = MFMA16(A1f.v, b21.v, a2);
                f32x4 a3 = {mi3, mi3, mi3, mi3};
                a3 = MFMA16(A0f.v, b30.v, a3);
                a3 = MFMA16(A1f.v, b31.v, a3);
                c0 = a0[0]; c1 = a1[0]; c2 = a2[0]; c3 = a3[0];
            }
        }
        __syncthreads();   // barrier D
    }

    // ---- epilogue: out = (sigmoid(xa_T@Wo+bo) * c_T) @ Wfc + bfc ----
    if (w == 15) {
        const float cown = (q == 0) ? c0 : (q == 1) ? c1 : (q == 2) ? c2 : c3;
        cfin_lds[l] = cown;                              // all-lane write
        LDS_FENCE();
        const float* xa = x_a + ((size_t)b * T_ + (T_ - 1)) * AUX_;
        float L = bo[l];
#pragma unroll
        for (int a = 0; a < AUX_; ++a) L = fmaf(xa[a], Wo[a * H_ + l], L);
        const float o = 1.0f / (1.0f + __expf(-L));
        const float cfin = cfin_lds[l];
        float p = (o * cfin) * Wfc[l];
        p = sum64_uni(p);
        if (l == 0) out[b] = p + bfc[0];
        out[B_ + b * H_ + l] = cfin;                     // c_final, coalesced
    }
}

} // namespace

extern "C" void kernel_launch(void* const* d_in, const int* in_sizes, int n_in,
                              void* d_out, int out_size, void* d_ws, size_t ws_size,
                              hipStream_t stream) {
    const float* x_m = (const float*)d_in[0];
    const float* x_a = (const float*)d_in[1];
    const float* Wj  = (const float*)d_in[2];
    const float* bj  = (const float*)d_in[3];
    const float* Wr  = (const float*)d_in[4];
    const float* br  = (const float*)d_in[5];
    const float* Wo  = (const float*)d_in[6];
    const float* bo  = (const float*)d_in[7];
    const float* Wfc = (const float*)d_in[8];
    const float* bfc = (const float*)d_in[9];
    float* out = (float*)d_out;

    hipLaunchKernelGGL(nomc_prep, dim3(NTILE), dim3(64), 0, stream,
                       Wj, bj, Wr, br, d_ws);
    hipLaunchKernelGGL(nomc_main, dim3(B_), dim3(1024), 0, stream,
                       x_m, x_a, Wo, bo, Wfc, bfc, d_ws, out);
}

// Round 6
// 360.742 us; speedup vs baseline: 1.0197x; 1.0197x over previous
//
#include <hip/hip_runtime.h>

// NoMCOutModel round 20: r19's balanced produce WITHOUT the register
// prefetch (which spilled).
// r19 post-mortem: FETCH 6.4MB -> 679MB, WRITE 72KB -> 91MB: the it-top
// 18-tile register prefetch (tr[4][4]+tj+biases ~90 VGPR on top of live
// state) blew the 128-VGPR cap from __launch_bounds__(1024,4); compiler
// spilled the arrays to scratch -> every "prefetch" became an HBM round
// trip; 189 -> 304us. The balance idea was never actually tested.
// This round: keep the balanced decomposition -- every wave owns exactly
// 18 tiles (4 R groups {4w..4w+3} + half of J group 64+(w>>1), halves
// merged via ph[16][16] + barrier) with compile-time trip counts and no
// gg<64 branch -- but load each tile/bias just-in-time inside the
// unrolled loops, exactly like r18's codegen. Scan/m_in/prep/epilogue:
// identical to r18.

namespace {

constexpr int B_ = 256, T_ = 256, M_ = 8, AUX_ = 32, H_ = 64;
constexpr int NTILE = 288;               // (64*64 + 8*64)/16 logit col-tiles
constexpr float LOG2E = 1.4426950408889634f;

typedef __fp16 f16x2 __attribute__((ext_vector_type(2)));
typedef __fp16 f16x8 __attribute__((ext_vector_type(8)));
typedef float  f32x4 __attribute__((ext_vector_type(4)));
typedef int    i32x4 __attribute__((ext_vector_type(4)));

union V8 { f16x8 v; f16x2 p[4]; i32x4 i; };

#if __has_builtin(__builtin_amdgcn_exp2f)
#define EXP2(x) __builtin_amdgcn_exp2f(x)
#else
#define EXP2(x) exp2f(x)
#endif

#define MFMA16(A, Bv, C) __builtin_amdgcn_mfma_f32_16x16x32_f16((A), (Bv), (C), 0, 0, 0)

__device__ __forceinline__ float dot2(f16x2 a, f16x2 b, float c) {
    return __builtin_amdgcn_fdot2(a, b, c, false);
}

template <int CTRL>
__device__ __forceinline__ float dpp_add(float v) {
    int t = __builtin_amdgcn_update_dpp(0, __builtin_bit_cast(int, v),
                                        CTRL, 0xf, 0xf, true);
    return v + __builtin_bit_cast(float, t);
}
__device__ __forceinline__ float sum16_all(float v) {
    v = dpp_add<0xB1>(v);   // quad_perm [1,0,3,2]
    v = dpp_add<0x4E>(v);   // quad_perm [2,3,0,1]
    v = dpp_add<0x141>(v);  // row_half_mirror
    v = dpp_add<0x140>(v);  // row_mirror
    return v;
}
__device__ __forceinline__ float sum64_uni(float v) {
    v = dpp_add<0x111>(v); v = dpp_add<0x112>(v); v = dpp_add<0x114>(v);
    v = dpp_add<0x118>(v); v = dpp_add<0x142>(v); v = dpp_add<0x143>(v);
    return __builtin_bit_cast(float,
        __builtin_amdgcn_readlane(__builtin_bit_cast(int, v), 63));
}

// RNE pair-pack: every lane ends with (f16(chat[2P]), f16(chat[2P+1])) where
// P = lane>>1. Own value is converted RNE ((__fp16) cast = v_cvt_f16_f32),
// then quad_perm DPP broadcasts the even/odd pair members to both lanes.
__device__ __forceinline__ int pack_pair_rne(float v) {
    const int hv = (int)__builtin_bit_cast(unsigned short, (__fp16)v);
    const int ev = __builtin_amdgcn_update_dpp(0, hv, 0xA0, 0xf, 0xf, true); // [0,0,2,2]
    const int ov = __builtin_amdgcn_update_dpp(0, hv, 0xF5, 0xf, 0xf, true); // [1,1,3,3]
    return ev | (ov << 16);
}

#define LDS_FENCE() __asm__ volatile("s_waitcnt lgkmcnt(0)" ::: "memory")

// ---------------- prep: W -> f16 MFMA B-frag layout in ws ----------------
// ws[gt*1024 + lane*16] : f16x8 frag, B[k = (lane>>4)*8 + j][n = gt*16+(lane&15)]
// ws + 288*1024 : float bias[4608] (log2e-scaled)
__global__ __launch_bounds__(64)
void nomc_prep(const float* __restrict__ Wj, const float* __restrict__ bj,
               const float* __restrict__ Wr, const float* __restrict__ br,
               void* __restrict__ ws)
{
    const int gt = blockIdx.x;           // 0..287
    const int l = threadIdx.x, q = l >> 4, l15 = l & 15;
    const float* src; const float* bsrc; int stride;
    if (gt < 256) { const int n = gt * 16 + l15;        src = Wr + n; bsrc = br + n; stride = 4096; }
    else          { const int n = (gt - 256) * 16 + l15; src = Wj + n; bsrc = bj + n; stride = 512; }
    V8 v;
#pragma unroll
    for (int j = 0; j < 4; ++j) {
        const float f0 = src[(q * 8 + 2 * j)     * stride] * LOG2E;
        const float f1 = src[(q * 8 + 2 * j + 1) * stride] * LOG2E;
        v.p[j] = __builtin_amdgcn_cvt_pkrtz(f0, f1);
    }
    *(i32x4*)((char*)ws + (size_t)gt * 1024 + l * 16) = v.i;
    if (l < 16)
        ((float*)((char*)ws + NTILE * 1024))[gt * 16 + l] = bsrc[0] * LOG2E;
}

// ---------------- main ----------------
__global__ __launch_bounds__(1024, 4)
void nomc_main(const float* __restrict__ x_m, const float* __restrict__ x_a,
               const float* __restrict__ Wo, const float* __restrict__ bo,
               const float* __restrict__ Wfc, const float* __restrict__ bfc,
               const void* __restrict__ ws, float* __restrict__ out)
{
    const int b = blockIdx.x, tid = threadIdx.x;
    const int w = tid >> 6, l = tid & 63, q = l >> 4, l15 = l & 15;

    __shared__ __align__(16) __fp16 RT[16][8][64][8];   // 131072 B  RT[t][h>>3][k][(h&7)^((t>>2)<<1)]=e
    __shared__ __align__(16) __fp16 JT[16][64][8];      //  16384 B  JT[t][k][m^((t>>2)<<1)]=e_j
    __shared__ float sinv[16][64];                      //   4096 B  1/rowsum(R)
    __shared__ __align__(16) __fp16 xj[16][8];          //    256 B  [t][m^((t>>2)<<1)]=xm/s_j
    __shared__ __align__(16) __fp16 minL[16][64];       //   2048 B  m_in[t][k]
    __shared__ float xm_lds[T_][M_];                    //   8192 B
    __shared__ float cfin_lds[H_];                      //    256 B
    __shared__ float ph[16][16];                        //   1024 B  J half-rowsums [wave][t]
    // total 163328 <= 163840

    {   // stage x_m once
        const float* xmb = x_m + (size_t)b * T_ * M_;
        for (int i = tid; i < T_ * M_; i += 1024) (&xm_lds[0][0])[i] = xmb[i];
    }
    __syncthreads();

    // Balanced produce: wave w owns R groups {4w..4w+3} (16 tiles) + half of
    // J group 64+(w>>1): tiles tt in {0,1} for even w, {2,3} for odd w.
    const char* wsb = (const char*)ws;
    const float* wbias = (const float*)(wsb + NTILE * 1024);
    const int a_sh = w >> 1;                 // shared J group -> m = a_sh
    const int tb = (w & 1) ? 2 : 0;          // J tile base

    const int sx = q << 1;               // store-side bank swizzle (= (t>>2)<<1)

    float c0 = 0.f, c1 = 0.f, c2 = 0.f, c3 = 0.f;   // c[kt*16 + l15], q-replicated

    for (int it = 0; it < 16; ++it) {
        // ================= produce: 16 timesteps of exp(logits) =================
        V8 af;
        {   // A-frag: row = l15 -> t = it*16+l15; k = q*8+j
            const float* xa = x_a + ((size_t)b * T_ + it * 16 + l15) * AUX_ + q * 8;
            const f32x4 x0 = *(const f32x4*)xa;
            const f32x4 x1 = *(const f32x4*)(xa + 4);
            af.p[0] = __builtin_amdgcn_cvt_pkrtz(x0.x, x0.y);
            af.p[1] = __builtin_amdgcn_cvt_pkrtz(x0.z, x0.w);
            af.p[2] = __builtin_amdgcn_cvt_pkrtz(x1.x, x1.y);
            af.p[3] = __builtin_amdgcn_cvt_pkrtz(x1.z, x1.w);
        }

        // ---- J half: 2 tiles of group 64+a_sh (loads just-in-time) ----
        {
            float ej0 = 0.f, ej1 = 0.f, ej2 = 0.f, ej3 = 0.f;
#pragma unroll
            for (int s = 0; s < 2; ++s) {
                const int tt = tb + s;
                const int gt = (64 + a_sh) * 4 + tt;
                V8 bf; bf.i = *(const i32x4*)(wsb + (size_t)gt * 1024 + l * 16);
                const float bv = wbias[gt * 16 + l15];
                f32x4 acc = {bv, bv, bv, bv};
                acc = MFMA16(af.v, bf.v, acc);
                const float e0 = EXP2(acc[0]), e1 = EXP2(acc[1]);
                const float e2 = EXP2(acc[2]), e3 = EXP2(acc[3]);
                const int kk = (tt << 4) + l15;
                const int mp = a_sh ^ sx;
                JT[q * 4 + 0][kk][mp] = (__fp16)e0;
                JT[q * 4 + 1][kk][mp] = (__fp16)e1;
                JT[q * 4 + 2][kk][mp] = (__fp16)e2;
                JT[q * 4 + 3][kk][mp] = (__fp16)e3;
                ej0 += e0; ej1 += e1; ej2 += e2; ej3 += e3;
            }
            ej0 = sum16_all(ej0); ej1 = sum16_all(ej1);
            ej2 = sum16_all(ej2); ej3 = sum16_all(ej3);
            if (l15 == 0) {
                ph[w][q * 4 + 0] = ej0;
                ph[w][q * 4 + 1] = ej1;
                ph[w][q * 4 + 2] = ej2;
                ph[w][q * 4 + 3] = ej3;
            }
        }
        __syncthreads();   // barrier A: ph visible

        // ---- 4 full R groups (loads just-in-time) ----
#pragma unroll
        for (int g = 0; g < 4; ++g) {
            const int gg = w * 4 + g;                    // 0..63
            float es0 = 0.f, es1 = 0.f, es2 = 0.f, es3 = 0.f;
#pragma unroll
            for (int tt = 0; tt < 4; ++tt) {
                const int gt = gg * 4 + tt;
                V8 bf; bf.i = *(const i32x4*)(wsb + (size_t)gt * 1024 + l * 16);
                const float bv = wbias[gt * 16 + l15];
                f32x4 acc = {bv, bv, bv, bv};
                acc = MFMA16(af.v, bf.v, acc);
                const float e0 = EXP2(acc[0]), e1 = EXP2(acc[1]);
                const float e2 = EXP2(acc[2]), e3 = EXP2(acc[3]);
                const int kk = (tt << 4) + l15;
                const int hb = gg >> 3, p = (gg & 7) ^ sx;  // swizzled slot
                RT[q * 4 + 0][hb][kk][p] = (__fp16)e0;
                RT[q * 4 + 1][hb][kk][p] = (__fp16)e1;
                RT[q * 4 + 2][hb][kk][p] = (__fp16)e2;
                RT[q * 4 + 3][hb][kk][p] = (__fp16)e3;
                es0 += e0; es1 += e1; es2 += e2; es3 += e3;
            }
            const float sr0 = sum16_all(es0), sr1 = sum16_all(es1);
            const float sr2 = sum16_all(es2), sr3 = sum16_all(es3);
            if (l15 == 0) {
                sinv[q * 4 + 0][gg] = __builtin_amdgcn_rcpf(sr0);
                sinv[q * 4 + 1][gg] = __builtin_amdgcn_rcpf(sr1);
                sinv[q * 4 + 2][gg] = __builtin_amdgcn_rcpf(sr2);
                sinv[q * 4 + 3][gg] = __builtin_amdgcn_rcpf(sr3);
            }
        }

        // ---- J finalize: merge half-rowsums, write xj (even wave only) ----
        if ((w & 1) == 0 && l15 == 0) {
#pragma unroll
            for (int r = 0; r < 4; ++r) {
                const int t = q * 4 + r;
                const float tot = ph[w][t] + ph[w + 1][t];
                xj[t][a_sh ^ sx] =
                    (__fp16)(xm_lds[it * 16 + t][a_sh] * __builtin_amdgcn_rcpf(tot));
            }
        }
        __syncthreads();   // barrier B: produce complete

        // ====== m_in pass (parallel, c-independent): minL[t][k] = xj[t].JT[t][k] ======
        // JT and xj carry the SAME (w>>2)-dependent k-permutation inside each
        // 16B chunk, so the dot2 pairs still line up.
        {
            V8 jv; jv.v = *(const f16x8*)&JT[w][l][0];
            V8 xv; xv.v = *(const f16x8*)&xj[w][0];
            float s = 0.f;
            s = dot2(jv.p[0], xv.p[0], s);
            s = dot2(jv.p[1], xv.p[1], s);
            s = dot2(jv.p[2], xv.p[2], s);
            s = dot2(jv.p[3], xv.p[3], s);
            minL[w][l] = (__fp16)s;
        }
        __syncthreads();   // barrier C

        // ================= scan: 16 serial MFMA matvecs (wave 15) =================
        // cbuf-free: chat pair-packed in-register (RNE), redistributed by
        // bpermute from the SERVING lane (lane 2P holds chat pair P).
        if (w == 15) {
            const int ab = q << 5;              // A0 byte base = lane 8q
            for (int u = 0; u < 16; ++u) {
                const int sig = (u >> 2) & 3;   // matches producer swizzle
                // ---- c-independent prefetch (no fences -> compiler pipelines) ----
                const float mi0 = (float)minL[u][l15];
                const float mi1 = (float)minL[u][16 + l15];
                const float mi2 = (float)minL[u][32 + l15];
                const float mi3 = (float)minL[u][48 + l15];
                const float svl = sinv[u][l];
                V8 b00, b01, b10, b11, b20, b21, b30, b31;
                b00.v = *(const f16x8*)&RT[u][q][l15][0];
                b01.v = *(const f16x8*)&RT[u][4 + q][l15][0];
                b10.v = *(const f16x8*)&RT[u][q][16 + l15][0];
                b11.v = *(const f16x8*)&RT[u][4 + q][16 + l15][0];
                b20.v = *(const f16x8*)&RT[u][q][32 + l15][0];
                b21.v = *(const f16x8*)&RT[u][4 + q][32 + l15][0];
                b30.v = *(const f16x8*)&RT[u][q][48 + l15][0];
                b31.v = *(const f16x8*)&RT[u][4 + q][48 + l15][0];
                // ---- chat_l = c[l] * sinv[u][l]  (the r15 cbuf value, in-reg) ----
                const float cown = (q == 0) ? c0 : (q == 1) ? c1 : (q == 2) ? c2 : c3;
                const int spk = pack_pair_rne(cown * svl);  // lane pair 2P,2P+1 -> chat pair P
                // ---- A-frags via bpermute: A0 pair jp <- lane 8q+2(jp^sig);
                //      A1 pair jp <- lane 32+8q+2(jp^sig) (offset 128 folds) ----
                V8 A0f, A1f;
                A0f.i[0] = __builtin_amdgcn_ds_bpermute(ab + ((0 ^ sig) << 3), spk);
                A0f.i[1] = __builtin_amdgcn_ds_bpermute(ab + ((1 ^ sig) << 3), spk);
                A0f.i[2] = __builtin_amdgcn_ds_bpermute(ab + ((2 ^ sig) << 3), spk);
                A0f.i[3] = __builtin_amdgcn_ds_bpermute(ab + ((3 ^ sig) << 3), spk);
                A1f.i[0] = __builtin_amdgcn_ds_bpermute(128 + ab + ((0 ^ sig) << 3), spk);
                A1f.i[1] = __builtin_amdgcn_ds_bpermute(128 + ab + ((1 ^ sig) << 3), spk);
                A1f.i[2] = __builtin_amdgcn_ds_bpermute(128 + ab + ((2 ^ sig) << 3), spk);
                A1f.i[3] = __builtin_amdgcn_ds_bpermute(128 + ab + ((3 ^ sig) << 3), spk);
                // ---- 2-deep MFMA chains, C-init = m_in ----
                f32x4 a0 = {mi0, mi0, mi0, mi0};
                a0 = MFMA16(A0f.v, b00.v, a0);
                a0 = MFMA16(A1f.v, b01.v, a0);
                f32x4 a1 = {mi1, mi1, mi1, mi1};
                a1 = MFMA16(A0f.v, b10.v, a1);
                a1 = MFMA16(A1f.v, b11.v, a1);
                f32x4 a2 = {mi2, mi2, mi2, mi2};
                a2 = MFMA16(A0f.v, b20.v, a2);
                a2 = MFMA16(A1f.v, b21.v, a2);
                f32x4 a3 = {mi3, mi3, mi3, mi3};
                a3 = MFMA16(A0f.v, b30.v, a3);
                a3 = MFMA16(A1f.v, b31.v, a3);
                c0 = a0[0]; c1 = a1[0]; c2 = a2[0]; c3 = a3[0];
            }
        }
        __syncthreads();   // barrier D
    }

    // ---- epilogue: out = (sigmoid(xa_T@Wo+bo) * c_T) @ Wfc + bfc ----
    if (w == 15) {
        const float cown = (q == 0) ? c0 : (q == 1) ? c1 : (q == 2) ? c2 : c3;
        cfin_lds[l] = cown;                              // all-lane write
        LDS_FENCE();
        const float* xa = x_a + ((size_t)b * T_ + (T_ - 1)) * AUX_;
        float L = bo[l];
#pragma unroll
        for (int a = 0; a < AUX_; ++a) L = fmaf(xa[a], Wo[a * H_ + l], L);
        const float o = 1.0f / (1.0f + __expf(-L));
        const float cfin = cfin_lds[l];
        float p = (o * cfin) * Wfc[l];
        p = sum64_uni(p);
        if (l == 0) out[b] = p + bfc[0];
        out[B_ + b * H_ + l] = cfin;                     // c_final, coalesced
    }
}

} // namespace

extern "C" void kernel_launch(void* const* d_in, const int* in_sizes, int n_in,
                              void* d_out, int out_size, void* d_ws, size_t ws_size,
                              hipStream_t stream) {
    const float* x_m = (const float*)d_in[0];
    const float* x_a = (const float*)d_in[1];
    const float* Wj  = (const float*)d_in[2];
    const float* bj  = (const float*)d_in[3];
    const float* Wr  = (const float*)d_in[4];
    const float* br  = (const float*)d_in[5];
    const float* Wo  = (const float*)d_in[6];
    const float* bo  = (const float*)d_in[7];
    const float* Wfc = (const float*)d_in[8];
    const float* bfc = (const float*)d_in[9];
    float* out = (float*)d_out;

    hipLaunchKernelGGL(nomc_prep, dim3(NTILE), dim3(64), 0, stream,
                       Wj, bj, Wr, br, d_ws);
    hipLaunchKernelGGL(nomc_main, dim3(B_), dim3(1024), 0, stream,
                       x_m, x_a, Wo, bo, Wfc, bfc, d_ws, out);
}

// Round 7
// 231.415 us; speedup vs baseline: 1.5895x; 1.5589x over previous
//
#include <hip/hip_runtime.h>

// NoMCOutModel round 21: balanced produce with unroll-1 outer R loop (spill
// fix). r20 post-mortem: spill persisted after removing the explicit
// prefetch (FETCH 644MB, WRITE 95MB) -> root cause is the FULL UNROLL of
// the 4-group R loop: with compile-time addresses the scheduler hoists all
// 16 tile loads (+biases) to the loop head ~= 80+ VGPRs in flight; the
// allocator pins at 64 VGPR under __launch_bounds__(1024,4) and spills the
// rest to scratch. r18 dodged this only because its runtime ngrp loop made
// addresses unhoistable. Fix: keep the balanced 18-tiles/wave decomposition
// (4 R groups {4w..4w+3} + half J group, ph[16][16] merge + barrier) but
// '#pragma unroll 1' the outer R-group loop -- runtime g blocks cross-group
// hoisting; inner 4-tile loop stays unrolled (r18's exact codegen shape).
// Scan/m_in/prep/epilogue: identical to r18.

namespace {

constexpr int B_ = 256, T_ = 256, M_ = 8, AUX_ = 32, H_ = 64;
constexpr int NTILE = 288;               // (64*64 + 8*64)/16 logit col-tiles
constexpr float LOG2E = 1.4426950408889634f;

typedef __fp16 f16x2 __attribute__((ext_vector_type(2)));
typedef __fp16 f16x8 __attribute__((ext_vector_type(8)));
typedef float  f32x4 __attribute__((ext_vector_type(4)));
typedef int    i32x4 __attribute__((ext_vector_type(4)));

union V8 { f16x8 v; f16x2 p[4]; i32x4 i; };

#if __has_builtin(__builtin_amdgcn_exp2f)
#define EXP2(x) __builtin_amdgcn_exp2f(x)
#else
#define EXP2(x) exp2f(x)
#endif

#define MFMA16(A, Bv, C) __builtin_amdgcn_mfma_f32_16x16x32_f16((A), (Bv), (C), 0, 0, 0)

__device__ __forceinline__ float dot2(f16x2 a, f16x2 b, float c) {
    return __builtin_amdgcn_fdot2(a, b, c, false);
}

template <int CTRL>
__device__ __forceinline__ float dpp_add(float v) {
    int t = __builtin_amdgcn_update_dpp(0, __builtin_bit_cast(int, v),
                                        CTRL, 0xf, 0xf, true);
    return v + __builtin_bit_cast(float, t);
}
__device__ __forceinline__ float sum16_all(float v) {
    v = dpp_add<0xB1>(v);   // quad_perm [1,0,3,2]
    v = dpp_add<0x4E>(v);   // quad_perm [2,3,0,1]
    v = dpp_add<0x141>(v);  // row_half_mirror
    v = dpp_add<0x140>(v);  // row_mirror
    return v;
}
__device__ __forceinline__ float sum64_uni(float v) {
    v = dpp_add<0x111>(v); v = dpp_add<0x112>(v); v = dpp_add<0x114>(v);
    v = dpp_add<0x118>(v); v = dpp_add<0x142>(v); v = dpp_add<0x143>(v);
    return __builtin_bit_cast(float,
        __builtin_amdgcn_readlane(__builtin_bit_cast(int, v), 63));
}

// RNE pair-pack: every lane ends with (f16(chat[2P]), f16(chat[2P+1])) where
// P = lane>>1. Own value is converted RNE ((__fp16) cast = v_cvt_f16_f32),
// then quad_perm DPP broadcasts the even/odd pair members to both lanes.
__device__ __forceinline__ int pack_pair_rne(float v) {
    const int hv = (int)__builtin_bit_cast(unsigned short, (__fp16)v);
    const int ev = __builtin_amdgcn_update_dpp(0, hv, 0xA0, 0xf, 0xf, true); // [0,0,2,2]
    const int ov = __builtin_amdgcn_update_dpp(0, hv, 0xF5, 0xf, 0xf, true); // [1,1,3,3]
    return ev | (ov << 16);
}

#define LDS_FENCE() __asm__ volatile("s_waitcnt lgkmcnt(0)" ::: "memory")

// ---------------- prep: W -> f16 MFMA B-frag layout in ws ----------------
// ws[gt*1024 + lane*16] : f16x8 frag, B[k = (lane>>4)*8 + j][n = gt*16+(lane&15)]
// ws + 288*1024 : float bias[4608] (log2e-scaled)
__global__ __launch_bounds__(64)
void nomc_prep(const float* __restrict__ Wj, const float* __restrict__ bj,
               const float* __restrict__ Wr, const float* __restrict__ br,
               void* __restrict__ ws)
{
    const int gt = blockIdx.x;           // 0..287
    const int l = threadIdx.x, q = l >> 4, l15 = l & 15;
    const float* src; const float* bsrc; int stride;
    if (gt < 256) { const int n = gt * 16 + l15;        src = Wr + n; bsrc = br + n; stride = 4096; }
    else          { const int n = (gt - 256) * 16 + l15; src = Wj + n; bsrc = bj + n; stride = 512; }
    V8 v;
#pragma unroll
    for (int j = 0; j < 4; ++j) {
        const float f0 = src[(q * 8 + 2 * j)     * stride] * LOG2E;
        const float f1 = src[(q * 8 + 2 * j + 1) * stride] * LOG2E;
        v.p[j] = __builtin_amdgcn_cvt_pkrtz(f0, f1);
    }
    *(i32x4*)((char*)ws + (size_t)gt * 1024 + l * 16) = v.i;
    if (l < 16)
        ((float*)((char*)ws + NTILE * 1024))[gt * 16 + l] = bsrc[0] * LOG2E;
}

// ---------------- main ----------------
__global__ __launch_bounds__(1024, 4)
void nomc_main(const float* __restrict__ x_m, const float* __restrict__ x_a,
               const float* __restrict__ Wo, const float* __restrict__ bo,
               const float* __restrict__ Wfc, const float* __restrict__ bfc,
               const void* __restrict__ ws, float* __restrict__ out)
{
    const int b = blockIdx.x, tid = threadIdx.x;
    const int w = tid >> 6, l = tid & 63, q = l >> 4, l15 = l & 15;

    __shared__ __align__(16) __fp16 RT[16][8][64][8];   // 131072 B  RT[t][h>>3][k][(h&7)^((t>>2)<<1)]=e
    __shared__ __align__(16) __fp16 JT[16][64][8];      //  16384 B  JT[t][k][m^((t>>2)<<1)]=e_j
    __shared__ float sinv[16][64];                      //   4096 B  1/rowsum(R)
    __shared__ __align__(16) __fp16 xj[16][8];          //    256 B  [t][m^((t>>2)<<1)]=xm/s_j
    __shared__ __align__(16) __fp16 minL[16][64];       //   2048 B  m_in[t][k]
    __shared__ float xm_lds[T_][M_];                    //   8192 B
    __shared__ float cfin_lds[H_];                      //    256 B
    __shared__ float ph[16][16];                        //   1024 B  J half-rowsums [wave][t]
    // total 163328 <= 163840

    {   // stage x_m once
        const float* xmb = x_m + (size_t)b * T_ * M_;
        for (int i = tid; i < T_ * M_; i += 1024) (&xm_lds[0][0])[i] = xmb[i];
    }
    __syncthreads();

    // Balanced produce: wave w owns R groups {4w..4w+3} (16 tiles) + half of
    // J group 64+(w>>1): tiles tt in {0,1} for even w, {2,3} for odd w.
    const char* wsb = (const char*)ws;
    const float* wbias = (const float*)(wsb + NTILE * 1024);
    const int a_sh = w >> 1;                 // shared J group -> m = a_sh
    const int tb = (w & 1) ? 2 : 0;          // J tile base

    const int sx = q << 1;               // store-side bank swizzle (= (t>>2)<<1)

    float c0 = 0.f, c1 = 0.f, c2 = 0.f, c3 = 0.f;   // c[kt*16 + l15], q-replicated

    for (int it = 0; it < 16; ++it) {
        // ================= produce: 16 timesteps of exp(logits) =================
        V8 af;
        {   // A-frag: row = l15 -> t = it*16+l15; k = q*8+j
            const float* xa = x_a + ((size_t)b * T_ + it * 16 + l15) * AUX_ + q * 8;
            const f32x4 x0 = *(const f32x4*)xa;
            const f32x4 x1 = *(const f32x4*)(xa + 4);
            af.p[0] = __builtin_amdgcn_cvt_pkrtz(x0.x, x0.y);
            af.p[1] = __builtin_amdgcn_cvt_pkrtz(x0.z, x0.w);
            af.p[2] = __builtin_amdgcn_cvt_pkrtz(x1.x, x1.y);
            af.p[3] = __builtin_amdgcn_cvt_pkrtz(x1.z, x1.w);
        }

        // ---- J half: 2 tiles of group 64+a_sh (loads just-in-time) ----
        {
            float ej0 = 0.f, ej1 = 0.f, ej2 = 0.f, ej3 = 0.f;
#pragma unroll
            for (int s = 0; s < 2; ++s) {
                const int tt = tb + s;
                const int gt = (64 + a_sh) * 4 + tt;
                V8 bf; bf.i = *(const i32x4*)(wsb + (size_t)gt * 1024 + l * 16);
                const float bv = wbias[gt * 16 + l15];
                f32x4 acc = {bv, bv, bv, bv};
                acc = MFMA16(af.v, bf.v, acc);
                const float e0 = EXP2(acc[0]), e1 = EXP2(acc[1]);
                const float e2 = EXP2(acc[2]), e3 = EXP2(acc[3]);
                const int kk = (tt << 4) + l15;
                const int mp = a_sh ^ sx;
                JT[q * 4 + 0][kk][mp] = (__fp16)e0;
                JT[q * 4 + 1][kk][mp] = (__fp16)e1;
                JT[q * 4 + 2][kk][mp] = (__fp16)e2;
                JT[q * 4 + 3][kk][mp] = (__fp16)e3;
                ej0 += e0; ej1 += e1; ej2 += e2; ej3 += e3;
            }
            ej0 = sum16_all(ej0); ej1 = sum16_all(ej1);
            ej2 = sum16_all(ej2); ej3 = sum16_all(ej3);
            if (l15 == 0) {
                ph[w][q * 4 + 0] = ej0;
                ph[w][q * 4 + 1] = ej1;
                ph[w][q * 4 + 2] = ej2;
                ph[w][q * 4 + 3] = ej3;
            }
        }
        __syncthreads();   // barrier A: ph visible

        // ---- 4 full R groups; unroll 1 so per-group loads can't be hoisted
        //      across groups (the r19/r20 spill trigger) ----
#pragma unroll 1
        for (int g = 0; g < 4; ++g) {
            const int gg = w * 4 + g;                    // 0..63
            float es0 = 0.f, es1 = 0.f, es2 = 0.f, es3 = 0.f;
#pragma unroll
            for (int tt = 0; tt < 4; ++tt) {
                const int gt = gg * 4 + tt;
                V8 bf; bf.i = *(const i32x4*)(wsb + (size_t)gt * 1024 + l * 16);
                const float bv = wbias[gt * 16 + l15];
                f32x4 acc = {bv, bv, bv, bv};
                acc = MFMA16(af.v, bf.v, acc);
                const float e0 = EXP2(acc[0]), e1 = EXP2(acc[1]);
                const float e2 = EXP2(acc[2]), e3 = EXP2(acc[3]);
                const int kk = (tt << 4) + l15;
                const int hb = gg >> 3, p = (gg & 7) ^ sx;  // swizzled slot
                RT[q * 4 + 0][hb][kk][p] = (__fp16)e0;
                RT[q * 4 + 1][hb][kk][p] = (__fp16)e1;
                RT[q * 4 + 2][hb][kk][p] = (__fp16)e2;
                RT[q * 4 + 3][hb][kk][p] = (__fp16)e3;
                es0 += e0; es1 += e1; es2 += e2; es3 += e3;
            }
            const float sr0 = sum16_all(es0), sr1 = sum16_all(es1);
            const float sr2 = sum16_all(es2), sr3 = sum16_all(es3);
            if (l15 == 0) {
                sinv[q * 4 + 0][gg] = __builtin_amdgcn_rcpf(sr0);
                sinv[q * 4 + 1][gg] = __builtin_amdgcn_rcpf(sr1);
                sinv[q * 4 + 2][gg] = __builtin_amdgcn_rcpf(sr2);
                sinv[q * 4 + 3][gg] = __builtin_amdgcn_rcpf(sr3);
            }
        }

        // ---- J finalize: merge half-rowsums, write xj (even wave only) ----
        if ((w & 1) == 0 && l15 == 0) {
#pragma unroll
            for (int r = 0; r < 4; ++r) {
                const int t = q * 4 + r;
                const float tot = ph[w][t] + ph[w + 1][t];
                xj[t][a_sh ^ sx] =
                    (__fp16)(xm_lds[it * 16 + t][a_sh] * __builtin_amdgcn_rcpf(tot));
            }
        }
        __syncthreads();   // barrier B: produce complete

        // ====== m_in pass (parallel, c-independent): minL[t][k] = xj[t].JT[t][k] ======
        // JT and xj carry the SAME (w>>2)-dependent k-permutation inside each
        // 16B chunk, so the dot2 pairs still line up.
        {
            V8 jv; jv.v = *(const f16x8*)&JT[w][l][0];
            V8 xv; xv.v = *(const f16x8*)&xj[w][0];
            float s = 0.f;
            s = dot2(jv.p[0], xv.p[0], s);
            s = dot2(jv.p[1], xv.p[1], s);
            s = dot2(jv.p[2], xv.p[2], s);
            s = dot2(jv.p[3], xv.p[3], s);
            minL[w][l] = (__fp16)s;
        }
        __syncthreads();   // barrier C

        // ================= scan: 16 serial MFMA matvecs (wave 15) =================
        // cbuf-free: chat pair-packed in-register (RNE), redistributed by
        // bpermute from the SERVING lane (lane 2P holds chat pair P).
        if (w == 15) {
            const int ab = q << 5;              // A0 byte base = lane 8q
            for (int u = 0; u < 16; ++u) {
                const int sig = (u >> 2) & 3;   // matches producer swizzle
                // ---- c-independent prefetch (no fences -> compiler pipelines) ----
                const float mi0 = (float)minL[u][l15];
                const float mi1 = (float)minL[u][16 + l15];
                const float mi2 = (float)minL[u][32 + l15];
                const float mi3 = (float)minL[u][48 + l15];
                const float svl = sinv[u][l];
                V8 b00, b01, b10, b11, b20, b21, b30, b31;
                b00.v = *(const f16x8*)&RT[u][q][l15][0];
                b01.v = *(const f16x8*)&RT[u][4 + q][l15][0];
                b10.v = *(const f16x8*)&RT[u][q][16 + l15][0];
                b11.v = *(const f16x8*)&RT[u][4 + q][16 + l15][0];
                b20.v = *(const f16x8*)&RT[u][q][32 + l15][0];
                b21.v = *(const f16x8*)&RT[u][4 + q][32 + l15][0];
                b30.v = *(const f16x8*)&RT[u][q][48 + l15][0];
                b31.v = *(const f16x8*)&RT[u][4 + q][48 + l15][0];
                // ---- chat_l = c[l] * sinv[u][l]  (the r15 cbuf value, in-reg) ----
                const float cown = (q == 0) ? c0 : (q == 1) ? c1 : (q == 2) ? c2 : c3;
                const int spk = pack_pair_rne(cown * svl);  // lane pair 2P,2P+1 -> chat pair P
                // ---- A-frags via bpermute: A0 pair jp <- lane 8q+2(jp^sig);
                //      A1 pair jp <- lane 32+8q+2(jp^sig) (offset 128 folds) ----
                V8 A0f, A1f;
                A0f.i[0] = __builtin_amdgcn_ds_bpermute(ab + ((0 ^ sig) << 3), spk);
                A0f.i[1] = __builtin_amdgcn_ds_bpermute(ab + ((1 ^ sig) << 3), spk);
                A0f.i[2] = __builtin_amdgcn_ds_bpermute(ab + ((2 ^ sig) << 3), spk);
                A0f.i[3] = __builtin_amdgcn_ds_bpermute(ab + ((3 ^ sig) << 3), spk);
                A1f.i[0] = __builtin_amdgcn_ds_bpermute(128 + ab + ((0 ^ sig) << 3), spk);
                A1f.i[1] = __builtin_amdgcn_ds_bpermute(128 + ab + ((1 ^ sig) << 3), spk);
                A1f.i[2] = __builtin_amdgcn_ds_bpermute(128 + ab + ((2 ^ sig) << 3), spk);
                A1f.i[3] = __builtin_amdgcn_ds_bpermute(128 + ab + ((3 ^ sig) << 3), spk);
                // ---- 2-deep MFMA chains, C-init = m_in ----
                f32x4 a0 = {mi0, mi0, mi0, mi0};
                a0 = MFMA16(A0f.v, b00.v, a0);
                a0 = MFMA16(A1f.v, b01.v, a0);
                f32x4 a1 = {mi1, mi1, mi1, mi1};
                a1 = MFMA16(A0f.v, b10.v, a1);
                a1 = MFMA16(A1f.v, b11.v, a1);
                f32x4 a2 = {mi2, mi2, mi2, mi2};
                a2 = MFMA16(A0f.v, b20.v, a2);
                a2 = MFMA16(A1f.v, b21.v, a2);
                f32x4 a3 = {mi3, mi3, mi3, mi3};
                a3 = MFMA16(A0f.v, b30.v, a3);
                a3 = MFMA16(A1f.v, b31.v, a3);
                c0 = a0[0]; c1 = a1[0]; c2 = a2[0]; c3 = a3[0];
            }
        }
        __syncthreads();   // barrier D
    }

    // ---- epilogue: out = (sigmoid(xa_T@Wo+bo) * c_T) @ Wfc + bfc ----
    if (w == 15) {
        const float cown = (q == 0) ? c0 : (q == 1) ? c1 : (q == 2) ? c2 : c3;
        cfin_lds[l] = cown;                              // all-lane write
        LDS_FENCE();
        const float* xa = x_a + ((size_t)b * T_ + (T_ - 1)) * AUX_;
        float L = bo[l];
#pragma unroll
        for (int a = 0; a < AUX_; ++a) L = fmaf(xa[a], Wo[a * H_ + l], L);
        const float o = 1.0f / (1.0f + __expf(-L));
        const float cfin = cfin_lds[l];
        float p = (o * cfin) * Wfc[l];
        p = sum64_uni(p);
        if (l == 0) out[b] = p + bfc[0];
        out[B_ + b * H_ + l] = cfin;                     // c_final, coalesced
    }
}

} // namespace

extern "C" void kernel_launch(void* const* d_in, const int* in_sizes, int n_in,
                              void* d_out, int out_size, void* d_ws, size_t ws_size,
                              hipStream_t stream) {
    const float* x_m = (const float*)d_in[0];
    const float* x_a = (const float*)d_in[1];
    const float* Wj  = (const float*)d_in[2];
    const float* bj  = (const float*)d_in[3];
    const float* Wr  = (const float*)d_in[4];
    const float* br  = (const float*)d_in[5];
    const float* Wo  = (const float*)d_in[6];
    const float* bo  = (const float*)d_in[7];
    const float* Wfc = (const float*)d_in[8];
    const float* bfc = (const float*)d_in[9];
    float* out = (float*)d_out;

    hipLaunchKernelGGL(nomc_prep, dim3(NTILE), dim3(64), 0, stream,
                       Wj, bj, Wr, br, d_ws);
    hipLaunchKernelGGL(nomc_main, dim3(B_), dim3(1024), 0, stream,
                       x_m, x_a, Wo, bo, Wfc, bfc, d_ws, out);
}